// Round 10
// baseline (355.298 us; speedup 1.0000x reference)
//
#include <hip/hip_runtime.h>
#include <stdint.h>

#define KPS 512
#define NBOX 1536
#define NBINS 1024
#define CAP 96          // bucket capacity; bins >= cutoff hold <= ~30 keys (3x margin)

// scale cell counts: 32*H*H*3
#define S13 16224
#define S26 64896
#define S52 259584
#define TOTCELL 340704

__device__ __forceinline__ uint32_t f2u(float x){ union{float f;uint32_t u;}v; v.f=x; return v.u; }
__device__ __forceinline__ float u2f(uint32_t x){ union{float f;uint32_t u;}v; v.u=x; return v.f; }

__device__ __forceinline__ int binOf(float s){
    int b = (int)((s - 0.6f) * 2560.0f);    // 1024 bins over (0.6, 1.0)
    if (b < 0) b = 0;
    if (b > NBINS-1) b = NBINS-1;
    return b;
}

__device__ __forceinline__ unsigned long long readlane64(unsigned long long v, int i){
    unsigned lo = (unsigned)__builtin_amdgcn_readlane((int)(unsigned)v, i);
    unsigned hi = (unsigned)__builtin_amdgcn_readlane((int)(unsigned)(v >> 32), i);
    return ((unsigned long long)hi << 32) | (unsigned long long)lo;
}

__global__ void k_init(int* hist, int* cnt){
    int id = blockIdx.x*256 + threadIdx.x;
    if (id < 3*NBINS) hist[id] = 0;
    if (id < 32) cnt[id] = 0;
}

// Score + direct bucket binning (verified): hist atomicAdd doubles as bucket
// cursor; atomics SPREAD over 3072 bins (R8 lesson: same-address device
// atomics ~100ns serialized — never per-item on one address).
__global__ void k_score(const float* __restrict__ o13, const float* __restrict__ o26,
                        const float* __restrict__ o52,
                        unsigned long long* __restrict__ bucket, int* __restrict__ hist){
    int id = blockIdx.x*256 + threadIdx.x;
    if (id >= TOTCELL) return;
    int scale, idl, H;
    const float* src;
    if (id < S13)            { scale=0; idl=id;            H=13; src=o13; }
    else if (id < S13+S26)   { scale=1; idl=id-S13;        H=26; src=o26; }
    else                     { scale=2; idl=id-(S13+S26);  H=52; src=o52; }
    int HW = H*H;
    int p  = idl / HW;
    int hw = idl - p*HW;
    int n  = p / 3;
    int a  = p - n*3;
    float x = src[(size_t)(n*255 + a*85)*HW + hw];
    float s = (float)(1.0 / (1.0 + exp(-(double)x)));   // correctly-rounded f32 sigmoid
    if (s > 0.6f){
        int cidx = (n*HW + hw)*3 + a;       // reference flat cell index
        unsigned long long key = ((unsigned long long)f2u(s) << 20)
            | ((unsigned long long)(2-scale) << 18)
            | (unsigned long long)(262143 - cidx);
        int slot = scale*NBINS + binOf(s);
        int pos = atomicAdd(&hist[slot], 1);
        if (pos < CAP) bucket[(size_t)slot*CAP + pos] = key;
    }
}

// Fused cutoff+gather+rank-sort: one block per scale (verified R6 kernel).
__global__ void __launch_bounds__(1024) k_selfin(const int* __restrict__ hist,
                        const unsigned long long* __restrict__ bucket,
                        unsigned long long* __restrict__ sel, int* __restrict__ cnt){
    int s = blockIdx.x, t = threadIdx.x;
    __shared__ int suf[NBINS];
    __shared__ unsigned long long un[640];      // <= 511 + CAP
    __shared__ int sB;
    int h = hist[s*NBINS + t];
    suf[t] = h; __syncthreads();
    for (int d = 1; d < NBINS; d <<= 1){        // in-place suffix scan
        int v = (t + d < NBINS) ? suf[t + d] : 0;
        __syncthreads();
        suf[t] += v;
        __syncthreads();
    }
    int total = suf[0];
    int A = (t < NBINS-1) ? suf[t+1] : 0;       // count strictly above bin t
    if (t == 0 && total < KPS) sB = -1;
    if (A < KPS && A + h >= KPS) sB = t;        // unique crossing when total>=KPS
    __syncthreads();
    int B = sB;
    int Bg = (B < 0) ? 0 : B;
    if (t + Bg < NBINS){
        int b = Bg + t;
        int cb = hist[s*NBINS + b]; if (cb > CAP) cb = CAP;
        int off = (b == NBINS-1) ? 0 : suf[b+1];
        for (int e = 0; e < cb; e++)
            un[off + e] = bucket[(size_t)(s*NBINS + b)*CAP + e];
    }
    __syncthreads();
    int hB = hist[s*NBINS + Bg]; if (hB > CAP) hB = CAP;
    int E = ((Bg == NBINS-1) ? 0 : suf[Bg+1]) + hB;   // gathered count
    int Nsel = (E < KPS) ? E : KPS;
    for (int e = t; e < E; e += 1024){
        unsigned long long k = un[e];
        int rank = 0;
        for (int q = 0; q < E; q++) rank += (un[q] > k) ? 1 : 0;
        if (rank < Nsel) sel[s*KPS + rank] = k;
    }
    if (t < KPS && t >= Nsel) sel[s*KPS + t] = 0ull;   // sentinels
    if (t == 0) cnt[s] = Nsel;
}

// FUSED decode+merge (blocks 0..95) ∥ masks (blocks 96..191) — both are
// independent consumers of sel, so one dispatch. Masks blocks SELF-RANK:
// broadcast LDS scan gives all 1536 ranks (~5us, parallel across blocks),
// geometry decoded from keys + gathered v1..v4 with the SAME f32 expression
// tree as decode -> bit-identical geometry; IoU body is the verified staged
// form (R8's masks body minus the fatal same-address edge atomics).
__global__ void __launch_bounds__(1024) k_decmask(
                         const float* __restrict__ o13, const float* __restrict__ o26,
                         const float* __restrict__ o52,
                         const float* __restrict__ a13, const float* __restrict__ a26,
                         const float* __restrict__ a52,
                         const unsigned long long* __restrict__ sel, const int* __restrict__ cnt,
                         float* __restrict__ sboxes, unsigned long long* __restrict__ vwords,
                         unsigned* __restrict__ Tcol, unsigned long long* __restrict__ diagR){
    __shared__ unsigned long long sk[NBOX];
    __shared__ float gx[NBOX], gy[NBOX], gw[NBOX], gh[NBOX];
    int t = threadIdx.x;
    int blk = blockIdx.x;
    for (int r = t; r < NBOX; r += 1024) sk[r] = sel[r];
    __syncthreads();
    if (blk < 96){
        // ---------------- decode path (verified R9 body) ----------------
        int wv = t >> 6, lane = t & 63;
        int b = blk*16 + wv;                 // [0, 1536)
        unsigned long long key = sk[b];
        int pc = 0;
        for (int q = lane; q < NBOX; q += 64){
            unsigned long long kq = sk[q];
            pc += (kq > key || (kq == key && q < b)) ? 1 : 0;
        }
        #pragma unroll
        for (int off = 32; off; off >>= 1) pc += __shfl_xor(pc, off);
        int rank = pc;                       // permutation of [0,NBOX)
        float* row = sboxes + rank*12;
        if ((key >> 20) == 0ull){            // sentinel
            if (lane < 9) row[lane] = 0.f;
        } else {
            int scale = 2 - (int)((key >> 18) & 3ull);
            int cidx  = 262143 - (int)(key & 0x3FFFFull);
            uint32_t sbits = (uint32_t)(key >> 20);
            const float* src; const float* anch; int H; float tt;
            if (scale == 0){ src=o13; anch=a13; H=13; tt=32.f; }
            else if (scale == 1){ src=o26; anch=a26; H=26; tt=16.f; }
            else { src=o52; anch=a52; H=52; tt=8.f; }
            int HW = H*H;
            int a  = cidx % 3;
            int hw = (cidx/3) % HW;
            int n  = cidx / (3*HW);
            int hh = hw / H;
            int ww = hw - hh*H;
            const float* cellbase = src + (size_t)(n*255 + a*85)*HW + hw;
            // argmax over 80 classes, tie -> lowest class index
            float bv = cellbase[(size_t)(5 + lane)*HW];
            int bi = lane;
            if (lane < 16){
                float v2 = cellbase[(size_t)(69 + lane)*HW];
                if (v2 > bv){ bv = v2; bi = 64 + lane; }
            }
            #pragma unroll
            for (int off=32; off; off>>=1){
                float vo = __shfl_xor(bv, off);
                int io = __shfl_xor(bi, off);
                if (vo > bv || (vo == bv && io < bi)){ bv = vo; bi = io; }
            }
            if (lane == 0){
                float v1 = cellbase[(size_t)1*HW];
                float v2 = cellbase[(size_t)2*HW];
                float v3 = cellbase[(size_t)3*HW];
                float v4 = cellbase[(size_t)4*HW];
                float cx = ((float)ww + v1) * tt / 416.0f;
                float cy = ((float)hh + v2) * tt / 416.0f;
                float e3 = (float)exp((double)v3);
                float e4 = (float)exp((double)v4);
                float bw = anch[a*2+0] * e3 / 416.0f;
                float bh = anch[a*2+1] * e4 / 416.0f;
                row[0] = (float)n;  row[1] = cx; row[2] = cy; row[3] = bw; row[4] = bh;
                row[5] = u2f(sbits); row[6] = (float)bi; row[7] = (float)hh; row[8] = (float)ww;
            }
        }
        if (blk == 0 && t < 24){
            int nv = cnt[0] + cnt[1] + cnt[2];   // valid keys sort to a contiguous prefix
            int rem = nv - t*64;
            vwords[t] = rem >= 64 ? ~0ull : (rem <= 0 ? 0ull : ((1ull << rem) - 1ull));
        }
    } else {
        // ---------------- masks path: self-rank + geometry + IoU ----------------
        // rank all 1536 boxes: thread handles boxes t and t+1024; every lane
        // reads the SAME sk[q] per iteration -> LDS broadcast (conflict-free).
        int b1 = t, b2 = t + 1024;
        unsigned long long k1 = sk[b1];
        unsigned long long k2 = (b2 < NBOX) ? sk[b2] : 0ull;
        int r1 = 0, r2 = 0;
        #pragma unroll 4
        for (int q = 0; q < NBOX; q++){
            unsigned long long kq = sk[q];
            r1 += (kq > k1 || (kq == k1 && q < b1)) ? 1 : 0;
            if (b2 < NBOX) r2 += (kq > k2 || (kq == k2 && q < b2)) ? 1 : 0;
        }
        // geometry decode (identical f32 expression tree as decode path)
        #pragma unroll
        for (int pass = 0; pass < 2; pass++){
            int b = pass ? b2 : b1;
            if (b >= NBOX) continue;
            unsigned long long key = pass ? k2 : k1;
            int rank = pass ? r2 : r1;
            float cx = 0.f, cy = 0.f, bw = 0.f, bh = 0.f;
            if ((key >> 20) != 0ull){
                int scale = 2 - (int)((key >> 18) & 3ull);
                int cidx  = 262143 - (int)(key & 0x3FFFFull);
                const float* src; const float* anch; int H; float tt;
                if (scale == 0){ src=o13; anch=a13; H=13; tt=32.f; }
                else if (scale == 1){ src=o26; anch=a26; H=26; tt=16.f; }
                else { src=o52; anch=a52; H=52; tt=8.f; }
                int HW = H*H;
                int a  = cidx % 3;
                int hw = (cidx/3) % HW;
                int n  = cidx / (3*HW);
                int hh = hw / H;
                int ww = hw - hh*H;
                const float* cellbase = src + (size_t)(n*255 + a*85)*HW + hw;
                float v1 = cellbase[(size_t)1*HW];
                float v2 = cellbase[(size_t)2*HW];
                float v3 = cellbase[(size_t)3*HW];
                float v4 = cellbase[(size_t)4*HW];
                cx = ((float)ww + v1) * tt / 416.0f;
                cy = ((float)hh + v2) * tt / 416.0f;
                float e3 = (float)exp((double)v3);
                float e4 = (float)exp((double)v4);
                bw = anch[a*2+0] * e3 / 416.0f;
                bh = anch[a*2+1] * e4 / 416.0f;
            }
            gx[rank] = cx; gy[rank] = cy; gw[rank] = bw; gh[rank] = bh;
        }
        __syncthreads();
        // IoU rows (verified staged body; NO edge atomics)
        int wv = t >> 6, lane = t & 63;
        int i = (blk - 96)*16 + wv;          // [0, 1536)
        int gi = i >> 6;
        float cxi = gx[i], cyi = gy[i], wi = gw[i], hi = gh[i];
        float x1i = cxi - wi/2.0f, y1i = cyi - hi/2.0f, x2i = cxi + wi/2.0f, y2i = cyi + hi/2.0f;
        float ari = fmaxf(x2i-x1i, 0.f) * fmaxf(y2i-y1i, 0.f);
        unsigned colbits = 0u;
        unsigned long long dm = 0ull;
        for (int c=0; c<24; c++){
            int j = c*64 + lane;
            float cxj = gx[j], cyj = gy[j], wj = gw[j], hj = gh[j];
            float x1j = cxj - wj/2.0f, y1j = cyj - hj/2.0f, x2j = cxj + wj/2.0f, y2j = cyj + hj/2.0f;
            float arj = fmaxf(x2j-x1j, 0.f) * fmaxf(y2j-y1j, 0.f);
            float ix = fmaxf(0.f, fminf(x2i, x2j) - fmaxf(x1i, x1j));
            float iy = fmaxf(0.f, fminf(y2i, y2j) - fmaxf(y1i, y1j));
            float inter = ix * iy;
            float iou = inter / fmaxf(fminf(ari, arj), 1e-9f);
            bool sb = (iou > 0.7f) && (j > i);
            colbits |= sb ? (1u << c) : 0u;
            unsigned long long m = __ballot(sb);
            if (c == gi) dm = m;
        }
        Tcol[(size_t)i*64 + lane] = colbits;
        if (lane == 0) diagR[i] = dm;
    }
}

// Greedy NMS scan (verified R6 kernel): suppressor-skip resolve + pipelined
// row loads + double-buffered partial merge (one barrier per tile).
__global__ void k_nms_out(const float* __restrict__ sboxes, const unsigned long long* __restrict__ vwords,
                          const unsigned long long* __restrict__ diagR, const unsigned* __restrict__ Tcol,
                          float* __restrict__ out){
    __shared__ unsigned long long keepw[24];
    __shared__ unsigned partial[2][4][64];
    int t = threadIdx.x;
    int wv = t >> 6, lane = t & 63;
    unsigned SS = 0u;      // bit g = box g*64+lane suppressed; identical in all waves
    unsigned long long rowR = diagR[lane];
    unsigned long long vcur = vwords[0];
    unsigned rows[16];
    {
        const unsigned* b0 = Tcol + (size_t)(wv*16)*64 + lane;
        #pragma unroll
        for (int i=0;i<16;i++) rows[i] = b0[i*64];
    }
    for (int g = 0; g < 24; g++){
        unsigned long long Rnext = (g < 23) ? diagR[(g+1)*64 + lane] : 0ull;
        unsigned long long vnext = (g < 23) ? vwords[g+1] : 0ull;
        bool live = (((vcur >> lane) & 1ull) != 0ull) && (((SS >> g) & 1u) == 0u);
        unsigned long long pend = __ballot(live);
        unsigned long long Z = __ballot(live && ((rowR & pend) != 0ull));
        unsigned long long kept = pend;
        unsigned long long iter = Z;
        while (iter){
            int i = __ffsll((long long)iter) - 1;
            iter &= iter - 1ull;
            if ((kept >> i) & 1ull){
                unsigned long long sup = readlane64(rowR, i);   // only bits > i
                kept &= ~sup;
                iter &= ~sup;
            }
        }
        if (t == 0) keepw[g] = kept;
        unsigned kbits = (unsigned)((kept >> (wv*16)) & 0xFFFFull);   // wave-uniform
        unsigned acc = 0u;
        #pragma unroll
        for (int i=0;i<16;i++) acc |= (0u - ((kbits >> i) & 1u)) & rows[i];
        if (g < 23){
            const unsigned* nb = Tcol + (size_t)((g+1)*64 + wv*16)*64 + lane;
            #pragma unroll
            for (int i=0;i<16;i++) rows[i] = nb[i*64];
        }
        partial[g & 1][wv][lane] = acc;
        __syncthreads();
        SS |= partial[g & 1][0][lane] | partial[g & 1][1][lane]
            | partial[g & 1][2][lane] | partial[g & 1][3][lane];
        rowR = Rnext; vcur = vnext;
    }
    for (int e=t; e<NBOX*9; e+=256){
        int r = e / 9;
        int c = e - r*9;
        bool kp = ((keepw[r >> 6] >> (r & 63)) & 1ull) != 0ull;
        out[e] = kp ? sboxes[r*12 + c] : 0.f;
    }
}

extern "C" void kernel_launch(void* const* d_in, const int* in_sizes, int n_in,
                              void* d_out, int out_size, void* d_ws, size_t ws_size,
                              hipStream_t stream){
    const float* o13 = (const float*)d_in[0];
    const float* o26 = (const float*)d_in[1];
    const float* o52 = (const float*)d_in[2];
    const float* a13 = (const float*)d_in[3];
    const float* a26 = (const float*)d_in[4];
    const float* a52 = (const float*)d_in[5];
    char* ws = (char*)d_ws;
    unsigned long long* bucket = (unsigned long long*)(ws);             // 3*1024*96*8 = 2,359,296
    unsigned* Tcol            = (unsigned*)(ws);                        // 393,216 — ALIASES bucket (dead after k_selfin)
    int* hist                 = (int*)(ws + 2359296);                   // 12,288
    int* cnt                  = (int*)(ws + 2371584);                   // 128
    unsigned long long* sel   = (unsigned long long*)(ws + 2371712);    // 12,288
    float* sboxes             = (float*)(ws + 2384000);                 // 73,728
    unsigned long long* vw    = (unsigned long long*)(ws + 2457728);    // 256
    unsigned long long* diagR = (unsigned long long*)(ws + 2457984);    // 12,288 (end ~2.47 MB)
    float* out = (float*)d_out;

    k_init     <<<12, 256, 0, stream>>>(hist, cnt);
    k_score    <<<(TOTCELL + 255)/256, 256, 0, stream>>>(o13, o26, o52, bucket, hist);
    k_selfin   <<<3, 1024, 0, stream>>>(hist, bucket, sel, cnt);
    k_decmask  <<<192, 1024, 0, stream>>>(o13, o26, o52, a13, a26, a52, sel, cnt, sboxes, vw, Tcol, diagR);
    k_nms_out  <<<1, 256, 0, stream>>>(sboxes, vw, diagR, Tcol, out);
}

// Round 12
// 235.998 us; speedup vs baseline: 1.5055x; 1.5055x over previous
//
#include <hip/hip_runtime.h>
#include <stdint.h>

#define KPS 512
#define NBOX 1536
#define NBINS 1024
#define CAP 96          // bucket capacity; bins >= cutoff hold <= ~30 keys (3x margin)

// scale cell counts: 32*H*H*3
#define S13 16224
#define S26 64896
#define S52 259584
#define TOTCELL 340704

__device__ __forceinline__ uint32_t f2u(float x){ union{float f;uint32_t u;}v; v.f=x; return v.u; }
__device__ __forceinline__ float u2f(uint32_t x){ union{float f;uint32_t u;}v; v.u=x; return v.f; }

__device__ __forceinline__ int binOf(float s){
    int b = (int)((s - 0.6f) * 2560.0f);    // 1024 bins over (0.6, 1.0)
    if (b < 0) b = 0;
    if (b > NBINS-1) b = NBINS-1;
    return b;
}

__device__ __forceinline__ unsigned long long readlane64(unsigned long long v, int i){
    unsigned lo = (unsigned)__builtin_amdgcn_readlane((int)(unsigned)v, i);
    unsigned hi = (unsigned)__builtin_amdgcn_readlane((int)(unsigned)(v >> 32), i);
    return ((unsigned long long)hi << 32) | (unsigned long long)lo;
}

__global__ void k_init(int* hist, int* cnt){
    int id = blockIdx.x*256 + threadIdx.x;
    if (id < 3*NBINS) hist[id] = 0;
    if (id < 32) cnt[id] = 0;
}

// Score + direct bucket binning (verified): hist atomicAdd doubles as bucket
// cursor; atomics SPREAD over 3072 bins (R8 lesson: same-address device
// atomics ~100ns serialized — never per-item on one address).
__global__ void k_score(const float* __restrict__ o13, const float* __restrict__ o26,
                        const float* __restrict__ o52,
                        unsigned long long* __restrict__ bucket, int* __restrict__ hist){
    int id = blockIdx.x*256 + threadIdx.x;
    if (id >= TOTCELL) return;
    int scale, idl, H;
    const float* src;
    if (id < S13)            { scale=0; idl=id;            H=13; src=o13; }
    else if (id < S13+S26)   { scale=1; idl=id-S13;        H=26; src=o26; }
    else                     { scale=2; idl=id-(S13+S26);  H=52; src=o52; }
    int HW = H*H;
    int p  = idl / HW;
    int hw = idl - p*HW;
    int n  = p / 3;
    int a  = p - n*3;
    float x = src[(size_t)(n*255 + a*85)*HW + hw];
    float s = (float)(1.0 / (1.0 + exp(-(double)x)));   // correctly-rounded f32 sigmoid
    if (s > 0.6f){
        int cidx = (n*HW + hw)*3 + a;       // reference flat cell index
        unsigned long long key = ((unsigned long long)f2u(s) << 20)
            | ((unsigned long long)(2-scale) << 18)
            | (unsigned long long)(262143 - cidx);
        int slot = scale*NBINS + binOf(s);
        int pos = atomicAdd(&hist[slot], 1);
        if (pos < CAP) bucket[(size_t)slot*CAP + pos] = key;
    }
}

// Fused cutoff+gather+rank-sort: one block per scale (verified R6 kernel).
__global__ void __launch_bounds__(1024) k_selfin(const int* __restrict__ hist,
                        const unsigned long long* __restrict__ bucket,
                        unsigned long long* __restrict__ sel, int* __restrict__ cnt){
    int s = blockIdx.x, t = threadIdx.x;
    __shared__ int suf[NBINS];
    __shared__ unsigned long long un[640];      // <= 511 + CAP
    __shared__ int sB;
    int h = hist[s*NBINS + t];
    suf[t] = h; __syncthreads();
    for (int d = 1; d < NBINS; d <<= 1){        // in-place suffix scan
        int v = (t + d < NBINS) ? suf[t + d] : 0;
        __syncthreads();
        suf[t] += v;
        __syncthreads();
    }
    int total = suf[0];
    int A = (t < NBINS-1) ? suf[t+1] : 0;       // count strictly above bin t
    if (t == 0 && total < KPS) sB = -1;
    if (A < KPS && A + h >= KPS) sB = t;        // unique crossing when total>=KPS
    __syncthreads();
    int B = sB;
    int Bg = (B < 0) ? 0 : B;
    if (t + Bg < NBINS){
        int b = Bg + t;
        int cb = hist[s*NBINS + b]; if (cb > CAP) cb = CAP;
        int off = (b == NBINS-1) ? 0 : suf[b+1];
        for (int e = 0; e < cb; e++)
            un[off + e] = bucket[(size_t)(s*NBINS + b)*CAP + e];
    }
    __syncthreads();
    int hB = hist[s*NBINS + Bg]; if (hB > CAP) hB = CAP;
    int E = ((Bg == NBINS-1) ? 0 : suf[Bg+1]) + hB;   // gathered count
    int Nsel = (E < KPS) ? E : KPS;
    for (int e = t; e < E; e += 1024){
        unsigned long long k = un[e];
        int rank = 0;
        for (int q = 0; q < E; q++) rank += (un[q] > k) ? 1 : 0;
        if (rank < Nsel) sel[s*KPS + rank] = k;
    }
    if (t < KPS && t >= Nsel) sel[s*KPS + t] = 0ull;   // sentinels
    if (t == 0) cnt[s] = Nsel;
}

// FUSED decode+merge (blocks 0..95) ∥ masks (blocks 96..191) — independent
// consumers of sel, one dispatch. Masks blocks rank via 3-WAY MERGE BINARY
// SEARCH (R2-verified: groups sorted desc, unique nonzero keys, zeros
// tie-break earlier-group-wins) — ~20 iterations/box, NOT the R10 per-thread
// 1536-scan (that was ~60us of VALU per block — R10 lesson).
__global__ void __launch_bounds__(1024) k_decmask(
                         const float* __restrict__ o13, const float* __restrict__ o26,
                         const float* __restrict__ o52,
                         const float* __restrict__ a13, const float* __restrict__ a26,
                         const float* __restrict__ a52,
                         const unsigned long long* __restrict__ sel, const int* __restrict__ cnt,
                         float* __restrict__ sboxes, unsigned long long* __restrict__ vwords,
                         unsigned* __restrict__ Tcol, unsigned long long* __restrict__ diagR){
    __shared__ unsigned long long sk[NBOX];
    __shared__ float gx[NBOX], gy[NBOX], gw[NBOX], gh[NBOX];
    int t = threadIdx.x;
    int blk = blockIdx.x;
    for (int r = t; r < NBOX; r += 1024) sk[r] = sel[r];
    __syncthreads();
    if (blk < 96){
        // ---------------- decode path (verified R9 body) ----------------
        int wv = t >> 6, lane = t & 63;
        int b = blk*16 + wv;                 // [0, 1536)
        unsigned long long key = sk[b];
        int pc = 0;
        for (int q = lane; q < NBOX; q += 64){
            unsigned long long kq = sk[q];
            pc += (kq > key || (kq == key && q < b)) ? 1 : 0;
        }
        #pragma unroll
        for (int off = 32; off; off >>= 1) pc += __shfl_xor(pc, off);
        int rank = pc;                       // permutation of [0,NBOX)
        float* row = sboxes + rank*12;
        if ((key >> 20) == 0ull){            // sentinel
            if (lane < 9) row[lane] = 0.f;
        } else {
            int scale = 2 - (int)((key >> 18) & 3ull);
            int cidx  = 262143 - (int)(key & 0x3FFFFull);
            uint32_t sbits = (uint32_t)(key >> 20);
            const float* src; const float* anch; int H; float tt;
            if (scale == 0){ src=o13; anch=a13; H=13; tt=32.f; }
            else if (scale == 1){ src=o26; anch=a26; H=26; tt=16.f; }
            else { src=o52; anch=a52; H=52; tt=8.f; }
            int HW = H*H;
            int a  = cidx % 3;
            int hw = (cidx/3) % HW;
            int n  = cidx / (3*HW);
            int hh = hw / H;
            int ww = hw - hh*H;
            const float* cellbase = src + (size_t)(n*255 + a*85)*HW + hw;
            // argmax over 80 classes, tie -> lowest class index
            float bv = cellbase[(size_t)(5 + lane)*HW];
            int bi = lane;
            if (lane < 16){
                float v2 = cellbase[(size_t)(69 + lane)*HW];
                if (v2 > bv){ bv = v2; bi = 64 + lane; }
            }
            #pragma unroll
            for (int off=32; off; off>>=1){
                float vo = __shfl_xor(bv, off);
                int io = __shfl_xor(bi, off);
                if (vo > bv || (vo == bv && io < bi)){ bv = vo; bi = io; }
            }
            if (lane == 0){
                float v1 = cellbase[(size_t)1*HW];
                float v2 = cellbase[(size_t)2*HW];
                float v3 = cellbase[(size_t)3*HW];
                float v4 = cellbase[(size_t)4*HW];
                float cx = ((float)ww + v1) * tt / 416.0f;
                float cy = ((float)hh + v2) * tt / 416.0f;
                float e3 = (float)exp((double)v3);
                float e4 = (float)exp((double)v4);
                float bw = anch[a*2+0] * e3 / 416.0f;
                float bh = anch[a*2+1] * e4 / 416.0f;
                row[0] = (float)n;  row[1] = cx; row[2] = cy; row[3] = bw; row[4] = bh;
                row[5] = u2f(sbits); row[6] = (float)bi; row[7] = (float)hh; row[8] = (float)ww;
            }
        }
        if (blk == 0 && t < 24){
            int nv = cnt[0] + cnt[1] + cnt[2];   // valid keys sort to a contiguous prefix
            int rem = nv - t*64;
            vwords[t] = rem >= 64 ? ~0ull : (rem <= 0 ? 0ull : ((1ull << rem) - 1ull));
        }
    } else {
        // ------- masks path: binary-search rank + geometry + IoU -------
        #pragma unroll
        for (int pass = 0; pass < 2; pass++){
            int b = pass ? (t + 1024) : t;
            if (b >= NBOX) continue;
            unsigned long long key = sk[b];
            int gph = b >> 9;
            int rank = b & 511;
            #pragma unroll
            for (int gg = 0; gg < 3; gg++){
                if (gg == gph) continue;
                const unsigned long long* a = sk + gg*512;
                bool geq = (gg < gph);          // equal keys (zeros): earlier group wins
                int lo = 0, hi = 512;
                while (lo < hi){
                    int mid = (lo + hi) >> 1;
                    bool adv = geq ? (a[mid] >= key) : (a[mid] > key);
                    if (adv) lo = mid + 1; else hi = mid;
                }
                rank += lo;
            }
            // geometry decode (identical f32 expression tree as decode path)
            float cx = 0.f, cy = 0.f, bw = 0.f, bh = 0.f;
            if ((key >> 20) != 0ull){
                int scale = 2 - (int)((key >> 18) & 3ull);
                int cidx  = 262143 - (int)(key & 0x3FFFFull);
                const float* src; const float* anch; int H; float tt;
                if (scale == 0){ src=o13; anch=a13; H=13; tt=32.f; }
                else if (scale == 1){ src=o26; anch=a26; H=26; tt=16.f; }
                else { src=o52; anch=a52; H=52; tt=8.f; }
                int HW = H*H;
                int a  = cidx % 3;
                int hw = (cidx/3) % HW;
                int n  = cidx / (3*HW);
                int hh = hw / H;
                int ww = hw - hh*H;
                const float* cellbase = src + (size_t)(n*255 + a*85)*HW + hw;
                float v1 = cellbase[(size_t)1*HW];
                float v2 = cellbase[(size_t)2*HW];
                float v3 = cellbase[(size_t)3*HW];
                float v4 = cellbase[(size_t)4*HW];
                cx = ((float)ww + v1) * tt / 416.0f;
                cy = ((float)hh + v2) * tt / 416.0f;
                float e3 = (float)exp((double)v3);
                float e4 = (float)exp((double)v4);
                bw = anch[a*2+0] * e3 / 416.0f;
                bh = anch[a*2+1] * e4 / 416.0f;
            }
            gx[rank] = cx; gy[rank] = cy; gw[rank] = bw; gh[rank] = bh;
        }
        __syncthreads();
        // IoU rows (verified staged body; NO edge atomics)
        int wv = t >> 6, lane = t & 63;
        int i = (blk - 96)*16 + wv;          // [0, 1536)
        int gi = i >> 6;
        float cxi = gx[i], cyi = gy[i], wi = gw[i], hi = gh[i];
        float x1i = cxi - wi/2.0f, y1i = cyi - hi/2.0f, x2i = cxi + wi/2.0f, y2i = cyi + hi/2.0f;
        float ari = fmaxf(x2i-x1i, 0.f) * fmaxf(y2i-y1i, 0.f);
        unsigned colbits = 0u;
        unsigned long long dm = 0ull;
        for (int c=0; c<24; c++){
            int j = c*64 + lane;
            float cxj = gx[j], cyj = gy[j], wj = gw[j], hj = gh[j];
            float x1j = cxj - wj/2.0f, y1j = cyj - hj/2.0f, x2j = cxj + wj/2.0f, y2j = cyj + hj/2.0f;
            float arj = fmaxf(x2j-x1j, 0.f) * fmaxf(y2j-y1j, 0.f);
            float ix = fmaxf(0.f, fminf(x2i, x2j) - fmaxf(x1i, x1j));
            float iy = fmaxf(0.f, fminf(y2i, y2j) - fmaxf(y1i, y1j));
            float inter = ix * iy;
            float iou = inter / fmaxf(fminf(ari, arj), 1e-9f);
            bool sb = (iou > 0.7f) && (j > i);
            colbits |= sb ? (1u << c) : 0u;
            unsigned long long m = __ballot(sb);
            if (c == gi) dm = m;
        }
        Tcol[(size_t)i*64 + lane] = colbits;
        if (lane == 0) diagR[i] = dm;
    }
}

// Greedy NMS scan (verified R6 kernel): suppressor-skip resolve + pipelined
// row loads + double-buffered partial merge (one barrier per tile).
__global__ void k_nms_out(const float* __restrict__ sboxes, const unsigned long long* __restrict__ vwords,
                          const unsigned long long* __restrict__ diagR, const unsigned* __restrict__ Tcol,
                          float* __restrict__ out){
    __shared__ unsigned long long keepw[24];
    __shared__ unsigned partial[2][4][64];
    int t = threadIdx.x;
    int wv = t >> 6, lane = t & 63;
    unsigned SS = 0u;      // bit g = box g*64+lane suppressed; identical in all waves
    unsigned long long rowR = diagR[lane];
    unsigned long long vcur = vwords[0];
    unsigned rows[16];
    {
        const unsigned* b0 = Tcol + (size_t)(wv*16)*64 + lane;
        #pragma unroll
        for (int i=0;i<16;i++) rows[i] = b0[i*64];
    }
    for (int g = 0; g < 24; g++){
        unsigned long long Rnext = (g < 23) ? diagR[(g+1)*64 + lane] : 0ull;
        unsigned long long vnext = (g < 23) ? vwords[g+1] : 0ull;
        bool live = (((vcur >> lane) & 1ull) != 0ull) && (((SS >> g) & 1u) == 0u);
        unsigned long long pend = __ballot(live);
        unsigned long long Z = __ballot(live && ((rowR & pend) != 0ull));
        unsigned long long kept = pend;
        unsigned long long iter = Z;
        while (iter){
            int i = __ffsll((long long)iter) - 1;
            iter &= iter - 1ull;
            if ((kept >> i) & 1ull){
                unsigned long long sup = readlane64(rowR, i);   // only bits > i
                kept &= ~sup;
                iter &= ~sup;
            }
        }
        if (t == 0) keepw[g] = kept;
        unsigned kbits = (unsigned)((kept >> (wv*16)) & 0xFFFFull);   // wave-uniform
        unsigned acc = 0u;
        #pragma unroll
        for (int i=0;i<16;i++) acc |= (0u - ((kbits >> i) & 1u)) & rows[i];
        if (g < 23){
            const unsigned* nb = Tcol + (size_t)((g+1)*64 + wv*16)*64 + lane;
            #pragma unroll
            for (int i=0;i<16;i++) rows[i] = nb[i*64];
        }
        partial[g & 1][wv][lane] = acc;
        __syncthreads();
        SS |= partial[g & 1][0][lane] | partial[g & 1][1][lane]
            | partial[g & 1][2][lane] | partial[g & 1][3][lane];
        rowR = Rnext; vcur = vnext;
    }
    for (int e=t; e<NBOX*9; e+=256){
        int r = e / 9;
        int c = e - r*9;
        bool kp = ((keepw[r >> 6] >> (r & 63)) & 1ull) != 0ull;
        out[e] = kp ? sboxes[r*12 + c] : 0.f;
    }
}

extern "C" void kernel_launch(void* const* d_in, const int* in_sizes, int n_in,
                              void* d_out, int out_size, void* d_ws, size_t ws_size,
                              hipStream_t stream){
    const float* o13 = (const float*)d_in[0];
    const float* o26 = (const float*)d_in[1];
    const float* o52 = (const float*)d_in[2];
    const float* a13 = (const float*)d_in[3];
    const float* a26 = (const float*)d_in[4];
    const float* a52 = (const float*)d_in[5];
    char* ws = (char*)d_ws;
    unsigned long long* bucket = (unsigned long long*)(ws);             // 3*1024*96*8 = 2,359,296
    unsigned* Tcol            = (unsigned*)(ws);                        // 393,216 — ALIASES bucket (dead after k_selfin)
    int* hist                 = (int*)(ws + 2359296);                   // 12,288
    int* cnt                  = (int*)(ws + 2371584);                   // 128
    unsigned long long* sel   = (unsigned long long*)(ws + 2371712);    // 12,288
    float* sboxes             = (float*)(ws + 2384000);                 // 73,728
    unsigned long long* vw    = (unsigned long long*)(ws + 2457728);    // 256
    unsigned long long* diagR = (unsigned long long*)(ws + 2457984);    // 12,288 (end ~2.47 MB)
    float* out = (float*)d_out;

    k_init     <<<12, 256, 0, stream>>>(hist, cnt);
    k_score    <<<(TOTCELL + 255)/256, 256, 0, stream>>>(o13, o26, o52, bucket, hist);
    k_selfin   <<<3, 1024, 0, stream>>>(hist, bucket, sel, cnt);
    k_decmask  <<<192, 1024, 0, stream>>>(o13, o26, o52, a13, a26, a52, sel, cnt, sboxes, vw, Tcol, diagR);
    k_nms_out  <<<1, 256, 0, stream>>>(sboxes, vw, diagR, Tcol, out);
}

// Round 13
// 230.515 us; speedup vs baseline: 1.5413x; 1.0238x over previous
//
#include <hip/hip_runtime.h>
#include <stdint.h>

#define KPS 512
#define NBOX 1536
#define NBINS 1024
#define CAP 96          // bucket capacity; bins >= cutoff hold <= ~30 keys (3x margin)

// scale cell counts: 32*H*H*3
#define S13 16224
#define S26 64896
#define S52 259584
#define TOTCELL 340704

__device__ __forceinline__ uint32_t f2u(float x){ union{float f;uint32_t u;}v; v.f=x; return v.u; }
__device__ __forceinline__ float u2f(uint32_t x){ union{float f;uint32_t u;}v; v.u=x; return v.f; }

__device__ __forceinline__ int binOf(float s){
    int b = (int)((s - 0.6f) * 2560.0f);    // 1024 bins over (0.6, 1.0)
    if (b < 0) b = 0;
    if (b > NBINS-1) b = NBINS-1;
    return b;
}

__device__ __forceinline__ unsigned long long readlane64(unsigned long long v, int i){
    unsigned lo = (unsigned)__builtin_amdgcn_readlane((int)(unsigned)v, i);
    unsigned hi = (unsigned)__builtin_amdgcn_readlane((int)(unsigned)(v >> 32), i);
    return ((unsigned long long)hi << 32) | (unsigned long long)lo;
}

__global__ void k_init(int* hist, int* cnt){
    int id = blockIdx.x*256 + threadIdx.x;
    if (id < 3*NBINS) hist[id] = 0;
    if (id < 32) cnt[id] = 0;
}

// Score + direct bucket binning (verified): hist atomicAdd doubles as bucket
// cursor; atomics SPREAD over 3072 bins (R8 lesson: same-address device
// atomics ~100ns serialized — never per-item on one address).
__global__ void k_score(const float* __restrict__ o13, const float* __restrict__ o26,
                        const float* __restrict__ o52,
                        unsigned long long* __restrict__ bucket, int* __restrict__ hist){
    int id = blockIdx.x*256 + threadIdx.x;
    if (id >= TOTCELL) return;
    int scale, idl, H;
    const float* src;
    if (id < S13)            { scale=0; idl=id;            H=13; src=o13; }
    else if (id < S13+S26)   { scale=1; idl=id-S13;        H=26; src=o26; }
    else                     { scale=2; idl=id-(S13+S26);  H=52; src=o52; }
    int HW = H*H;
    int p  = idl / HW;
    int hw = idl - p*HW;
    int n  = p / 3;
    int a  = p - n*3;
    float x = src[(size_t)(n*255 + a*85)*HW + hw];
    float s = (float)(1.0 / (1.0 + exp(-(double)x)));   // correctly-rounded f32 sigmoid
    if (s > 0.6f){
        int cidx = (n*HW + hw)*3 + a;       // reference flat cell index
        unsigned long long key = ((unsigned long long)f2u(s) << 20)
            | ((unsigned long long)(2-scale) << 18)
            | (unsigned long long)(262143 - cidx);
        int slot = scale*NBINS + binOf(s);
        int pos = atomicAdd(&hist[slot], 1);
        if (pos < CAP) bucket[(size_t)slot*CAP + pos] = key;
    }
}

// Fused cutoff+gather+rank-sort: one block per scale (verified R6 kernel).
__global__ void __launch_bounds__(1024) k_selfin(const int* __restrict__ hist,
                        const unsigned long long* __restrict__ bucket,
                        unsigned long long* __restrict__ sel, int* __restrict__ cnt){
    int s = blockIdx.x, t = threadIdx.x;
    __shared__ int suf[NBINS];
    __shared__ unsigned long long un[640];      // <= 511 + CAP
    __shared__ int sB;
    int h = hist[s*NBINS + t];
    suf[t] = h; __syncthreads();
    for (int d = 1; d < NBINS; d <<= 1){        // in-place suffix scan
        int v = (t + d < NBINS) ? suf[t + d] : 0;
        __syncthreads();
        suf[t] += v;
        __syncthreads();
    }
    int total = suf[0];
    int A = (t < NBINS-1) ? suf[t+1] : 0;       // count strictly above bin t
    if (t == 0 && total < KPS) sB = -1;
    if (A < KPS && A + h >= KPS) sB = t;        // unique crossing when total>=KPS
    __syncthreads();
    int B = sB;
    int Bg = (B < 0) ? 0 : B;
    if (t + Bg < NBINS){
        int b = Bg + t;
        int cb = hist[s*NBINS + b]; if (cb > CAP) cb = CAP;
        int off = (b == NBINS-1) ? 0 : suf[b+1];
        for (int e = 0; e < cb; e++)
            un[off + e] = bucket[(size_t)(s*NBINS + b)*CAP + e];
    }
    __syncthreads();
    int hB = hist[s*NBINS + Bg]; if (hB > CAP) hB = CAP;
    int E = ((Bg == NBINS-1) ? 0 : suf[Bg+1]) + hB;   // gathered count
    int Nsel = (E < KPS) ? E : KPS;
    for (int e = t; e < E; e += 1024){
        unsigned long long k = un[e];
        int rank = 0;
        for (int q = 0; q < E; q++) rank += (un[q] > k) ? 1 : 0;
        if (rank < Nsel) sel[s*KPS + rank] = k;
    }
    if (t < KPS && t >= Nsel) sel[s*KPS + t] = 0ull;   // sentinels
    if (t == 0) cnt[s] = Nsel;
}

// Fused decode+merge (96 blocks x 1024 = 16 waves, one box per wave):
// stage sel once per block, rank via wave scan, write straight to sboxes[rank].
// Block 0 emits analytic vwords.
__global__ void __launch_bounds__(1024) k_decode_merge(
                         const float* __restrict__ o13, const float* __restrict__ o26,
                         const float* __restrict__ o52,
                         const float* __restrict__ a13, const float* __restrict__ a26,
                         const float* __restrict__ a52,
                         const unsigned long long* __restrict__ sel, const int* __restrict__ cnt,
                         float* __restrict__ sboxes, unsigned long long* __restrict__ vwords){
    __shared__ unsigned long long sk[NBOX];
    int t = threadIdx.x;
    for (int r = t; r < NBOX; r += 1024) sk[r] = sel[r];
    __syncthreads();
    int wv = t >> 6, lane = t & 63;
    int b = blockIdx.x*16 + wv;          // [0, 1536)
    unsigned long long key = sk[b];
    int pc = 0;
    for (int q = lane; q < NBOX; q += 64){
        unsigned long long kq = sk[q];
        pc += (kq > key || (kq == key && q < b)) ? 1 : 0;
    }
    #pragma unroll
    for (int off = 32; off; off >>= 1) pc += __shfl_xor(pc, off);
    int rank = pc;                       // permutation of [0,NBOX)
    float* row = sboxes + rank*12;
    if ((key >> 20) == 0ull){            // sentinel
        if (lane < 9) row[lane] = 0.f;
    } else {
        int scale = 2 - (int)((key >> 18) & 3ull);
        int cidx  = 262143 - (int)(key & 0x3FFFFull);
        uint32_t sbits = (uint32_t)(key >> 20);
        const float* src; const float* anch; int H; float tt;
        if (scale == 0){ src=o13; anch=a13; H=13; tt=32.f; }
        else if (scale == 1){ src=o26; anch=a26; H=26; tt=16.f; }
        else { src=o52; anch=a52; H=52; tt=8.f; }
        int HW = H*H;
        int a  = cidx % 3;
        int hw = (cidx/3) % HW;
        int n  = cidx / (3*HW);
        int hh = hw / H;
        int ww = hw - hh*H;
        const float* cellbase = src + (size_t)(n*255 + a*85)*HW + hw;
        // argmax over 80 classes, tie -> lowest class index
        float bv = cellbase[(size_t)(5 + lane)*HW];
        int bi = lane;
        if (lane < 16){
            float v2 = cellbase[(size_t)(69 + lane)*HW];
            if (v2 > bv){ bv = v2; bi = 64 + lane; }
        }
        #pragma unroll
        for (int off=32; off; off>>=1){
            float vo = __shfl_xor(bv, off);
            int io = __shfl_xor(bi, off);
            if (vo > bv || (vo == bv && io < bi)){ bv = vo; bi = io; }
        }
        if (lane == 0){
            float v1 = cellbase[(size_t)1*HW];
            float v2 = cellbase[(size_t)2*HW];
            float v3 = cellbase[(size_t)3*HW];
            float v4 = cellbase[(size_t)4*HW];
            float cx = ((float)ww + v1) * tt / 416.0f;
            float cy = ((float)hh + v2) * tt / 416.0f;
            float e3 = (float)exp((double)v3);
            float e4 = (float)exp((double)v4);
            float bw = anch[a*2+0] * e3 / 416.0f;
            float bh = anch[a*2+1] * e4 / 416.0f;
            row[0] = (float)n;  row[1] = cx; row[2] = cy; row[3] = bw; row[4] = bh;
            row[5] = u2f(sbits); row[6] = (float)bi; row[7] = (float)hh; row[8] = (float)ww;
        }
    }
    if (blockIdx.x == 0 && t < 24){
        int nv = cnt[0] + cnt[1] + cnt[2];   // valid keys sort to a contiguous prefix
        int rem = nv - t*64;
        vwords[t] = rem >= 64 ? ~0ull : (rem <= 0 ? 0ull : ((1ull << rem) - 1ull));
    }
}

// Column-sliced suppression matrix (verified R6 form: 1536 blocks x 64, no atomics).
// Tcol[i*64 + j] bit c = sup(i, c*64+j); diagR[i] bit j = sup(i, gi*64+j).
__global__ void k_masks(const float* __restrict__ sboxes, unsigned* __restrict__ Tcol,
                        unsigned long long* __restrict__ diagR){
    int i = blockIdx.x;
    int lane = threadIdx.x;
    int gi = i >> 6;
    float cxi = sboxes[i*12+1], cyi = sboxes[i*12+2], wi = sboxes[i*12+3], hi = sboxes[i*12+4];
    float x1i = cxi - wi/2.0f, y1i = cyi - hi/2.0f, x2i = cxi + wi/2.0f, y2i = cyi + hi/2.0f;
    float ari = fmaxf(x2i-x1i, 0.f) * fmaxf(y2i-y1i, 0.f);
    unsigned colbits = 0u;
    for (int c=0; c<24; c++){
        int j = c*64 + lane;
        float cxj = sboxes[j*12+1], cyj = sboxes[j*12+2], wj = sboxes[j*12+3], hj = sboxes[j*12+4];
        float x1j = cxj - wj/2.0f, y1j = cyj - hj/2.0f, x2j = cxj + wj/2.0f, y2j = cyj + hj/2.0f;
        float arj = fmaxf(x2j-x1j, 0.f) * fmaxf(y2j-y1j, 0.f);
        float ix = fmaxf(0.f, fminf(x2i, x2j) - fmaxf(x1i, x1j));
        float iy = fmaxf(0.f, fminf(y2i, y2j) - fmaxf(y1i, y1j));
        float inter = ix * iy;
        float iou = inter / fmaxf(fminf(ari, arj), 1e-9f);
        bool sb = (iou > 0.7f) && (j > i);
        colbits |= sb ? (1u << c) : 0u;
    }
    Tcol[(size_t)i*64 + lane] = colbits;
    unsigned long long rowbits = __ballot(((colbits >> gi) & 1u) != 0u);
    if (lane == 0) diagR[i] = rowbits;
}

// Greedy NMS scan (verified R6 kernel): suppressor-skip resolve + pipelined
// row loads + double-buffered partial merge (one barrier per tile).
__global__ void k_nms_out(const float* __restrict__ sboxes, const unsigned long long* __restrict__ vwords,
                          const unsigned long long* __restrict__ diagR, const unsigned* __restrict__ Tcol,
                          float* __restrict__ out){
    __shared__ unsigned long long keepw[24];
    __shared__ unsigned partial[2][4][64];
    int t = threadIdx.x;
    int wv = t >> 6, lane = t & 63;
    unsigned SS = 0u;      // bit g = box g*64+lane suppressed; identical in all waves
    unsigned long long rowR = diagR[lane];
    unsigned long long vcur = vwords[0];
    unsigned rows[16];
    {
        const unsigned* b0 = Tcol + (size_t)(wv*16)*64 + lane;
        #pragma unroll
        for (int i=0;i<16;i++) rows[i] = b0[i*64];
    }
    for (int g = 0; g < 24; g++){
        unsigned long long Rnext = (g < 23) ? diagR[(g+1)*64 + lane] : 0ull;
        unsigned long long vnext = (g < 23) ? vwords[g+1] : 0ull;
        bool live = (((vcur >> lane) & 1ull) != 0ull) && (((SS >> g) & 1u) == 0u);
        unsigned long long pend = __ballot(live);
        unsigned long long Z = __ballot(live && ((rowR & pend) != 0ull));
        unsigned long long kept = pend;
        unsigned long long iter = Z;
        while (iter){
            int i = __ffsll((long long)iter) - 1;
            iter &= iter - 1ull;
            if ((kept >> i) & 1ull){
                unsigned long long sup = readlane64(rowR, i);   // only bits > i
                kept &= ~sup;
                iter &= ~sup;
            }
        }
        if (t == 0) keepw[g] = kept;
        unsigned kbits = (unsigned)((kept >> (wv*16)) & 0xFFFFull);   // wave-uniform
        unsigned acc = 0u;
        #pragma unroll
        for (int i=0;i<16;i++) acc |= (0u - ((kbits >> i) & 1u)) & rows[i];
        if (g < 23){
            const unsigned* nb = Tcol + (size_t)((g+1)*64 + wv*16)*64 + lane;
            #pragma unroll
            for (int i=0;i<16;i++) rows[i] = nb[i*64];
        }
        partial[g & 1][wv][lane] = acc;
        __syncthreads();
        SS |= partial[g & 1][0][lane] | partial[g & 1][1][lane]
            | partial[g & 1][2][lane] | partial[g & 1][3][lane];
        rowR = Rnext; vcur = vnext;
    }
    for (int e=t; e<NBOX*9; e+=256){
        int r = e / 9;
        int c = e - r*9;
        bool kp = ((keepw[r >> 6] >> (r & 63)) & 1ull) != 0ull;
        out[e] = kp ? sboxes[r*12 + c] : 0.f;
    }
}

extern "C" void kernel_launch(void* const* d_in, const int* in_sizes, int n_in,
                              void* d_out, int out_size, void* d_ws, size_t ws_size,
                              hipStream_t stream){
    const float* o13 = (const float*)d_in[0];
    const float* o26 = (const float*)d_in[1];
    const float* o52 = (const float*)d_in[2];
    const float* a13 = (const float*)d_in[3];
    const float* a26 = (const float*)d_in[4];
    const float* a52 = (const float*)d_in[5];
    char* ws = (char*)d_ws;
    unsigned long long* bucket = (unsigned long long*)(ws);             // 3*1024*96*8 = 2,359,296
    unsigned* Tcol            = (unsigned*)(ws);                        // 393,216 — ALIASES bucket (dead after k_selfin)
    int* hist                 = (int*)(ws + 2359296);                   // 12,288
    int* cnt                  = (int*)(ws + 2371584);                   // 128
    unsigned long long* sel   = (unsigned long long*)(ws + 2371712);    // 12,288
    float* sboxes             = (float*)(ws + 2384000);                 // 73,728
    unsigned long long* vw    = (unsigned long long*)(ws + 2457728);    // 256
    unsigned long long* diagR = (unsigned long long*)(ws + 2457984);    // 12,288 (end ~2.47 MB)
    float* out = (float*)d_out;

    k_init        <<<12, 256, 0, stream>>>(hist, cnt);
    k_score       <<<(TOTCELL + 255)/256, 256, 0, stream>>>(o13, o26, o52, bucket, hist);
    k_selfin      <<<3, 1024, 0, stream>>>(hist, bucket, sel, cnt);
    k_decode_merge<<<96, 1024, 0, stream>>>(o13, o26, o52, a13, a26, a52, sel, cnt, sboxes, vw);
    k_masks       <<<NBOX, 64, 0, stream>>>(sboxes, Tcol, diagR);
    k_nms_out     <<<1, 256, 0, stream>>>(sboxes, vw, diagR, Tcol, out);
}